// Round 15
// baseline (170.317 us; speedup 1.0000x reference)
//
#include <hip/hip_runtime.h>
#include <cstdint>

#define EPSV 1e-5f
#define SM_SCALE 0.044194173824159216f

typedef unsigned short u16;
typedef __attribute__((ext_vector_type(8))) short short8;
typedef __attribute__((ext_vector_type(4))) float f32x4;

__device__ __forceinline__ u16 f2bf(float f) {
  union { float f; uint32_t u; } v; v.f = f;
  return (u16)((v.u + 0x7FFFu + ((v.u >> 16) & 1u)) >> 16);
}

__device__ __forceinline__ void gload_lds16(const void* g, void* l) {
  __builtin_amdgcn_global_load_lds((const __attribute__((address_space(1))) void*)g,
                                   (__attribute__((address_space(3))) void*)l, 16, 0, 0);
}

__device__ __forceinline__ f32x4 mfma16(short8 a, short8 b, f32x4 c) {
  return __builtin_amdgcn_mfma_f32_16x16x32_bf16(a, b, c, 0, 0, 0);
}

// Swizzled LDS tile: [rows][32 bf16] (64B rows). 16B-slot s of row r holds
// global block (s ^ ((r>>1)&3)). Linear LDS dest + permuted GLOBAL source;
// read with same XOR. Verified conflict-free (R6/R7/R9/R12 PMC = 0).
__device__ __forceinline__ const short8* lds_frag(const u16* t, int row, int cc) {
  return reinterpret_cast<const short8*>(t + (size_t)(((row << 2) + (cc ^ ((row >> 1) & 3))) << 3));
}

#define WAIT_ENTER(N, is_tail)                                      \
  if (is_tail) { asm volatile("s_waitcnt vmcnt(0)" ::: "memory"); } \
  else         { asm volatile("s_waitcnt vmcnt(" #N ")" ::: "memory"); } \
  __builtin_amdgcn_s_barrier();                                     \
  asm volatile("" ::: "memory");

#define WAIT_EXIT()                                                 \
  asm volatile("s_waitcnt lgkmcnt(0)" ::: "memory");                \
  __builtin_amdgcn_s_barrier();                                     \
  asm volatile("" ::: "memory");

// ---------- Fused GroupNorm (stats + apply in one pass via LDS) ----------
__global__ __launch_bounds__(256) void gn_fused_k(const float* __restrict__ x,
                                                  const float* __restrict__ gw,
                                                  const float* __restrict__ gb,
                                                  u16* __restrict__ xn) {
  __shared__ float xs[8192];
  __shared__ float ls[4], lss[4];
  const int bg = blockIdx.x;                     // 0..2047
  const int g = bg & 31;
  const float* p = x + (size_t)bg * 8192;
  float s = 0.f, ss = 0.f;
#pragma unroll
  for (int i = 0; i < 8; ++i) {
    const int idx = i * 1024 + threadIdx.x * 4;
    float4 v = *reinterpret_cast<const float4*>(p + idx);
    *reinterpret_cast<float4*>(xs + idx) = v;
    s += v.x + v.y + v.z + v.w;
    ss += v.x * v.x + v.y * v.y + v.z * v.z + v.w * v.w;
  }
  for (int off = 32; off; off >>= 1) { s += __shfl_xor(s, off); ss += __shfl_xor(ss, off); }
  const int w = threadIdx.x >> 6;
  if ((threadIdx.x & 63) == 0) { ls[w] = s; lss[w] = ss; }
  __syncthreads();
  s = ls[0] + ls[1] + ls[2] + ls[3];
  ss = lss[0] + lss[1] + lss[2] + lss[3];
  const float inv_n = 1.0f / 8192.f;
  const float mean = s * inv_n;
  const float rstd = rsqrtf(ss * inv_n - mean * mean + EPSV);
#pragma unroll
  for (int j = 0; j < 4; ++j) {
    const int idx = j * 2048 + threadIdx.x * 8;
    const int c = g * 16 + (idx >> 9);
    const float sc = gw[c] * rstd;
    const float sh = gb[c] - mean * sc;
    u16 o[8];
#pragma unroll
    for (int e = 0; e < 8; ++e) o[e] = f2bf(xs[idx + e] * sc + sh);
    *reinterpret_cast<uint4*>(xn + (size_t)bg * 8192 + idx) = *reinterpret_cast<const uint4*>(o);
  }
}

// ---------- fp32 -> bf16 cast for the 3 weight matrices ----------
__global__ __launch_bounds__(256) void cast3_k(const float* __restrict__ a,
                                               const float* __restrict__ b2,
                                               const float* __restrict__ c,
                                               u16* __restrict__ oa, u16* __restrict__ ob,
                                               u16* __restrict__ oc) {
  const int which = blockIdx.x >> 7;
  const float* in = which == 0 ? a : (which == 1 ? b2 : c);
  u16* out = which == 0 ? oa : (which == 1 ? ob : oc);
  size_t base = (((size_t)(blockIdx.x & 127)) * 256 + threadIdx.x) * 8;
  float4 v0 = *reinterpret_cast<const float4*>(in + base);
  float4 v1 = *reinterpret_cast<const float4*>(in + base + 4);
  u16 o[8];
  o[0] = f2bf(v0.x); o[1] = f2bf(v0.y); o[2] = f2bf(v0.z); o[3] = f2bf(v0.w);
  o[4] = f2bf(v1.x); o[5] = f2bf(v1.y); o[6] = f2bf(v1.z); o[7] = f2bf(v1.w);
  *reinterpret_cast<uint4*>(out + base) = *reinterpret_cast<const uint4*>(o);
}

// ---------- Batched GEMM: out[b,m,n] = sum_k A[m,k]*B[n,k] (+bias) ----------
// 128x128 tile, 4 waves (64x64 each), swizzled LDS, depth-2 counted vmcnt.
// R9-proven config: (256,2), ~23 us per 512-cube dispatch.
// OUT_MODE: 0 = bf16 out + bias[n]; 1 = bf16 out + bias[m].
template <int OUT_MODE>
__global__ __launch_bounds__(256, 2) void gemm_abt_k(const u16* __restrict__ A, size_t sA,
                                                     const u16* __restrict__ Bm, size_t sB,
                                                     const float* __restrict__ bias,
                                                     u16* __restrict__ out, size_t sO) {
  __shared__ u16 As[2][4096];
  __shared__ u16 Bs[2][4096];     // 32 KB total
  const int d = blockIdx.x;
  const int t = d >> 3;
  const int b = (d & 7) * 8 + (t >> 4);          // XCD-bijective batch
  const int tile = t & 15;
  const int tm = (tile >> 2) * 128, tn = (tile & 3) * 128;
  const u16* Ab = A + (size_t)b * sA;
  const u16* Bb = Bm + (size_t)b * sB;
  const int tid = threadIdx.x, w = tid >> 6, lane = tid & 63;
  const int wr = (w >> 1) * 64, wc = (w & 1) * 64;
  const int srow = lane >> 2;
  const int ssw = ((lane & 3) ^ ((lane >> 3) & 3)) * 8;   // inverse-swizzled src col
  f32x4 acc[4][4] = {};

#define GM_STAGE(bb, k0)                                                       \
  {                                                                            \
    _Pragma("unroll")                                                          \
    for (int s2 = 0; s2 < 4; ++s2) {                                           \
      const int c = w * 4 + s2;                                                \
      if (c < 8)                                                               \
        gload_lds16(Ab + (size_t)(tm + c * 16 + srow) * 512 + (k0) + ssw,      \
                    &As[bb][c * 512]);                                         \
      else                                                                     \
        gload_lds16(Bb + (size_t)(tn + (c - 8) * 16 + srow) * 512 + (k0) + ssw,\
                    &Bs[bb][(c - 8) * 512]);                                   \
    }                                                                          \
  }

  GM_STAGE(0, 0);       // 4 loads/thread
  GM_STAGE(1, 32);      // 8 in flight
  for (int ts = 0; ts < 16; ++ts) {
    const int cur = ts & 1;
    WAIT_ENTER(4, ts == 15);
    const int frow = lane & 15, cc = lane >> 4;
    short8 af[4], bf[4];
#pragma unroll
    for (int i = 0; i < 4; ++i) {
      af[i] = *lds_frag(As[cur], wr + i * 16 + frow, cc);
      bf[i] = *lds_frag(Bs[cur], wc + i * 16 + frow, cc);
    }
#pragma unroll
    for (int mi = 0; mi < 4; ++mi)
#pragma unroll
      for (int ni = 0; ni < 4; ++ni)
        acc[mi][ni] = mfma16(af[mi], bf[ni], acc[mi][ni]);
    WAIT_EXIT();
    if (ts < 14) GM_STAGE(cur, (ts + 2) * 32);
  }
#undef GM_STAGE

  const int col0 = lane & 15, row0 = (lane >> 4) * 4;
#pragma unroll
  for (int mi = 0; mi < 4; ++mi)
#pragma unroll
    for (int ni = 0; ni < 4; ++ni) {
      const int gc = tn + wc + ni * 16 + col0;
      const float bv = (OUT_MODE == 0) ? bias[gc] : 0.f;
#pragma unroll
      for (int r = 0; r < 4; ++r) {
        const int gr = tm + wr + mi * 16 + row0 + r;
        float v = acc[mi][ni][r];
        if (OUT_MODE == 0) v += bv;
        if (OUT_MODE == 1) v += bias[gr];
        out[(size_t)b * sO + (size_t)gr * 512 + gc] = f2bf(v);
      }
    }
}

// ---------- Flash-fused attention: scores+softmax+PV in one kernel ----------
// 512 blocks (2/CU), 4 waves, QBLK=64. Phase A = R12's proven scores
// structure (K swizzle-staged, depth-2 counted vmcnt). Softmax. P bounced
// to LDS (aliases dead Ks region, XOR-swizzled for A-operand reads).
// Phase B: O = P * VT with VT read DIRECTLY from L2 into regs (zero in-block
// reuse -> no staging), 2-deep prefetch; no barriers needed in phase B.
// acc registers reused across phases (scores acc dead after P-write).
__global__ __launch_bounds__(256, 2) void attn_fused_k(const u16* __restrict__ Q,
                                                       const u16* __restrict__ K,
                                                       const u16* __restrict__ VT,
                                                       float* __restrict__ out) {
  // Phase A: Ks = smem[0..32767] (2 x 16384), Qs = smem[32768..36863] (2 x 2048)
  // Phase B: P  = smem[0..32767] (64 rows x 512 cols, swizzled)
  __shared__ u16 smem[36864];     // 72 KB
  __shared__ float rmax[4][64], rsum[4][64];
  const int d = blockIdx.x;       // 0..511
  const int t = d >> 3;
  const int b = (d & 7) * 8 + (t >> 3);   // XCD-bijective batch
  const int m0 = (t & 7) * 64;
  const u16* Qb = Q + (size_t)b * 262144 + (size_t)m0 * 512;
  const u16* Kb = K + (size_t)b * 262144;
  const u16* VTb = VT + (size_t)b * 262144;
  const int tid = threadIdx.x, kq = tid >> 6, lane = tid & 63;
  const int srow = lane >> 2;
  const int ssw = ((lane & 3) ^ ((lane >> 3) & 3)) * 8;
  const int frow = lane & 15, cc = lane >> 4;
  u16* Ks0 = smem;                // [2][16384]
  u16* Qs0 = smem + 32768;        // [2][2048]
  u16* Psm = smem;                // phase B alias
  f32x4 acc[4][8] = {};           // phase A: S[i-rowfrag][j-keyfrag]; reused as O in phase B

#define SC_STAGE(bb, k0)                                                       \
  {                                                                            \
    _Pragma("unroll")                                                          \
    for (int s2 = 0; s2 < 8; ++s2) {                                           \
      const int c = kq * 8 + s2;                                               \
      gload_lds16(Kb + (size_t)(c * 16 + srow) * 512 + (k0) + ssw,             \
                  Ks0 + (bb) * 16384 + c * 512);                               \
    }                                                                          \
    gload_lds16(Qb + (size_t)(kq * 16 + srow) * 512 + (k0) + ssw,              \
                Qs0 + (bb) * 2048 + kq * 512);                                 \
  }

  SC_STAGE(0, 0);       // 9 loads/thread
  SC_STAGE(1, 32);      // 18 in flight
  for (int ts = 0; ts < 16; ++ts) {
    const int cur = ts & 1;
    WAIT_ENTER(9, ts == 15);
    short8 aq[4];
#pragma unroll
    for (int i = 0; i < 4; ++i)
      aq[i] = *lds_frag(Qs0 + cur * 2048, i * 16 + frow, cc);
#pragma unroll
    for (int j = 0; j < 8; ++j) {
      short8 bk = *lds_frag(Ks0 + cur * 16384, kq * 128 + j * 16 + frow, cc);
#pragma unroll
      for (int i = 0; i < 4; ++i)
        acc[i][j] = mfma16(aq[i], bk, acc[i][j]);
    }
    WAIT_EXIT();
    if (ts < 14) SC_STAGE(cur, (ts + 2) * 32);
  }
#undef SC_STAGE

  // ---- softmax over 512 keys: per-wave partial (128 keys) + cross-wave combine
  float pm[4][4];
#pragma unroll
  for (int i = 0; i < 4; ++i)
#pragma unroll
    for (int r = 0; r < 4; ++r) pm[i][r] = -1e30f;
#pragma unroll
  for (int i = 0; i < 4; ++i)
#pragma unroll
    for (int j = 0; j < 8; ++j)
#pragma unroll
      for (int r = 0; r < 4; ++r) {
        float v = acc[i][j][r] * SM_SCALE;
        acc[i][j][r] = v;
        pm[i][r] = fmaxf(pm[i][r], v);
      }
#pragma unroll
  for (int off = 1; off < 16; off <<= 1)
#pragma unroll
    for (int i = 0; i < 4; ++i)
#pragma unroll
      for (int r = 0; r < 4; ++r) pm[i][r] = fmaxf(pm[i][r], __shfl_xor(pm[i][r], off));
  if ((lane & 15) == 0) {
#pragma unroll
    for (int i = 0; i < 4; ++i)
#pragma unroll
      for (int r = 0; r < 4; ++r)
        rmax[kq][i * 16 + (lane >> 4) * 4 + r] = pm[i][r];
  }
  __syncthreads();
#pragma unroll
  for (int i = 0; i < 4; ++i)
#pragma unroll
    for (int r = 0; r < 4; ++r) {
      const int row = i * 16 + (lane >> 4) * 4 + r;
      pm[i][r] = fmaxf(fmaxf(rmax[0][row], rmax[1][row]), fmaxf(rmax[2][row], rmax[3][row]));
    }
  float ps[4][4];
#pragma unroll
  for (int i = 0; i < 4; ++i)
#pragma unroll
    for (int r = 0; r < 4; ++r) ps[i][r] = 0.f;
#pragma unroll
  for (int i = 0; i < 4; ++i)
#pragma unroll
    for (int j = 0; j < 8; ++j)
#pragma unroll
      for (int r = 0; r < 4; ++r) {
        float e = __expf(acc[i][j][r] - pm[i][r]);
        acc[i][j][r] = e;
        ps[i][r] += e;
      }
#pragma unroll
  for (int off = 1; off < 16; off <<= 1)
#pragma unroll
    for (int i = 0; i < 4; ++i)
#pragma unroll
      for (int r = 0; r < 4; ++r) ps[i][r] += __shfl_xor(ps[i][r], off);
  if ((lane & 15) == 0) {
#pragma unroll
    for (int i = 0; i < 4; ++i)
#pragma unroll
      for (int r = 0; r < 4; ++r)
        rsum[kq][i * 16 + (lane >> 4) * 4 + r] = ps[i][r];
  }
  __syncthreads();
#pragma unroll
  for (int i = 0; i < 4; ++i)
#pragma unroll
    for (int r = 0; r < 4; ++r) {
      const int row = i * 16 + (lane >> 4) * 4 + r;
      ps[i][r] = 1.0f / (rsum[0][row] + rsum[1][row] + rsum[2][row] + rsum[3][row]);
    }

  // ---- VT prefetch (regs; latency hides under P-write + barrier) ----
  const u16* VTw = VTb + (size_t)(kq * 128 + frow) * 512 + cc * 8;
  short8 vA[8], vB[8];
#define VTLOAD(vr, k0)                                                         \
  {                                                                            \
    _Pragma("unroll")                                                          \
    for (int j = 0; j < 8; ++j)                                                \
      vr[j] = *reinterpret_cast<const short8*>(VTw + (size_t)j * 8192 + (k0)); \
  }
  VTLOAD(vA, 0);
  VTLOAD(vB, 32);

  // ---- P -> LDS (aliases Ks; all Ks reads completed at phase-A tail).
  // Swizzle: u16 idx = row*512 + ((col>>3) ^ (row&7))*8 + (col&7) -> the
  // phase-B A-operand read (16 rows x same slot) spreads over 8 slots = free.
#pragma unroll
  for (int i = 0; i < 4; ++i)
#pragma unroll
    for (int j = 0; j < 8; ++j) {
      const int col = kq * 128 + j * 16 + (lane & 15);
#pragma unroll
      for (int r = 0; r < 4; ++r) {
        const int row = i * 16 + (lane >> 4) * 4 + r;
        Psm[row * 512 + (((col >> 3) ^ (row & 7)) << 3) + (col & 7)] =
            f2bf(acc[i][j][r] * ps[i][r]);
      }
    }
  __syncthreads();

  // ---- Phase B: O[m, n] = sum_k P[m,k] * VT[n,k]; acc reused as O ----
#pragma unroll
  for (int i = 0; i < 4; ++i)
#pragma unroll
    for (int j = 0; j < 8; ++j) acc[i][j] = (f32x4){0.f, 0.f, 0.f, 0.f};

#define PV_BODY(vr, ts)                                                        \
  {                                                                            \
    short8 pa[4];                                                              \
    _Pragma("unroll")                                                          \
    for (int i = 0; i < 4; ++i) {                                              \
      const int prow = i * 16 + frow;                                          \
      const int slot = (ts) * 4 + cc;                                          \
      pa[i] = *reinterpret_cast<const short8*>(                                \
          &Psm[prow * 512 + ((slot ^ (prow & 7)) << 3)]);                      \
    }                                                                          \
    _Pragma("unroll")                                                          \
    for (int j = 0; j < 8; ++j)                                                \
      _Pragma("unroll")                                                        \
      for (int i = 0; i < 4; ++i)                                              \
        acc[i][j] = mfma16(pa[i], vr[j], acc[i][j]);                           \
    if ((ts) < 14) VTLOAD(vr, ((ts) + 2) * 32);                                \
  }

#pragma unroll
  for (int t2 = 0; t2 < 8; ++t2) {
    PV_BODY(vA, t2 * 2);
    PV_BODY(vB, t2 * 2 + 1);
  }
#undef PV_BODY
#undef VTLOAD

  // ---- O write (f32) ----
  float* ob = out + (size_t)b * 262144;
#pragma unroll
  for (int i = 0; i < 4; ++i)
#pragma unroll
    for (int j = 0; j < 8; ++j) {
      const int gcol = kq * 128 + j * 16 + (lane & 15);
#pragma unroll
      for (int r = 0; r < 4; ++r) {
        const int grow = m0 + i * 16 + (lane >> 4) * 4 + r;
        ob[(size_t)grow * 512 + gcol] = acc[i][j][r];
      }
    }
}

extern "C" void kernel_launch(void* const* d_in, const int* in_sizes, int n_in,
                              void* d_out, int out_size, void* d_ws, size_t ws_size,
                              hipStream_t stream) {
  const float* x = (const float*)d_in[0];
  const float* qw = (const float*)d_in[1];
  const float* qb = (const float*)d_in[2];
  const float* kw = (const float*)d_in[3];
  const float* kb = (const float*)d_in[4];
  const float* vw = (const float*)d_in[5];
  const float* vb = (const float*)d_in[6];
  const float* gnw = (const float*)d_in[7];
  const float* gnb = (const float*)d_in[8];

  char* ws = (char*)d_ws;
  u16* qwb = (u16*)(ws);
  u16* kwb = (u16*)(ws + 524288);
  u16* vwb = (u16*)(ws + 2 * 524288);
  u16* xn = (u16*)(ws + 4 * 524288);
  u16* Qb = xn + 16777216;
  u16* Kb = Qb + 16777216;
  u16* VT = Kb + 16777216;
  float* out = (float*)d_out;

  gn_fused_k<<<dim3(2048), dim3(256), 0, stream>>>(x, gnw, gnb, xn);
  cast3_k<<<dim3(384), dim3(256), 0, stream>>>(qw, kw, vw, qwb, kwb, vwb);
  // Q = xn qw^T + qb ; K = xn kw^T + kb (bf16, col bias) -- separate (R9 proven)
  gemm_abt_k<0><<<dim3(1024), dim3(256), 0, stream>>>(xn, (size_t)262144, qwb, (size_t)0, qb, Qb, (size_t)262144);
  gemm_abt_k<0><<<dim3(1024), dim3(256), 0, stream>>>(xn, (size_t)262144, kwb, (size_t)0, kb, Kb, (size_t)262144);
  // VT[b,d,c] = sum_k vw[d,k] xn[c,k] + vb[d] (bf16, row bias)
  gemm_abt_k<1><<<dim3(1024), dim3(256), 0, stream>>>(vwb, (size_t)0, xn, (size_t)262144, vb, VT, (size_t)262144);
  // out = softmax(Q K^T * scale) * V  -- fused (scores + softmax + PV)
  attn_fused_k<<<dim3(512), dim3(256), 0, stream>>>(Qb, Kb, VT, out);
}

// Round 17
// 148.072 us; speedup vs baseline: 1.1502x; 1.1502x over previous
//
#include <hip/hip_runtime.h>
#include <cstdint>

#define EPSV 1e-5f
#define SM_SCALE 0.044194173824159216f

typedef unsigned short u16;
typedef __attribute__((ext_vector_type(8))) short short8;
typedef __attribute__((ext_vector_type(4))) float f32x4;

__device__ __forceinline__ u16 f2bf(float f) {
  union { float f; uint32_t u; } v; v.f = f;
  return (u16)((v.u + 0x7FFFu + ((v.u >> 16) & 1u)) >> 16);
}

__device__ __forceinline__ void gload_lds16(const void* g, void* l) {
  __builtin_amdgcn_global_load_lds((const __attribute__((address_space(1))) void*)g,
                                   (__attribute__((address_space(3))) void*)l, 16, 0, 0);
}

__device__ __forceinline__ f32x4 mfma16(short8 a, short8 b, f32x4 c) {
  return __builtin_amdgcn_mfma_f32_16x16x32_bf16(a, b, c, 0, 0, 0);
}

// [rows][32 bf16] swizzled LDS (scores kernel): slot' = slot ^ ((row>>1)&3).
__device__ __forceinline__ const short8* lds_frag(const u16* t, int row, int cc) {
  return reinterpret_cast<const short8*>(t + (size_t)(((row << 2) + (cc ^ ((row >> 1) & 3))) << 3));
}

#define WAIT_ENTER(N, is_tail)                                      \
  if (is_tail) { asm volatile("s_waitcnt vmcnt(0)" ::: "memory"); } \
  else         { asm volatile("s_waitcnt vmcnt(" #N ")" ::: "memory"); } \
  __builtin_amdgcn_s_barrier();                                     \
  asm volatile("" ::: "memory");

#define WAIT_EXIT()                                                 \
  asm volatile("s_waitcnt lgkmcnt(0)" ::: "memory");                \
  __builtin_amdgcn_s_barrier();                                     \
  asm volatile("" ::: "memory");

// ---------- Fused GroupNorm ----------
__global__ __launch_bounds__(256) void gn_fused_k(const float* __restrict__ x,
                                                  const float* __restrict__ gw,
                                                  const float* __restrict__ gb,
                                                  u16* __restrict__ xn) {
  __shared__ float xs[8192];
  __shared__ float ls[4], lss[4];
  const int bg = blockIdx.x;
  const int g = bg & 31;
  const float* p = x + (size_t)bg * 8192;
  float s = 0.f, ss = 0.f;
#pragma unroll
  for (int i = 0; i < 8; ++i) {
    const int idx = i * 1024 + threadIdx.x * 4;
    float4 v = *reinterpret_cast<const float4*>(p + idx);
    *reinterpret_cast<float4*>(xs + idx) = v;
    s += v.x + v.y + v.z + v.w;
    ss += v.x * v.x + v.y * v.y + v.z * v.z + v.w * v.w;
  }
  for (int off = 32; off; off >>= 1) { s += __shfl_xor(s, off); ss += __shfl_xor(ss, off); }
  const int w = threadIdx.x >> 6;
  if ((threadIdx.x & 63) == 0) { ls[w] = s; lss[w] = ss; }
  __syncthreads();
  s = ls[0] + ls[1] + ls[2] + ls[3];
  ss = lss[0] + lss[1] + lss[2] + lss[3];
  const float inv_n = 1.0f / 8192.f;
  const float mean = s * inv_n;
  const float rstd = rsqrtf(ss * inv_n - mean * mean + EPSV);
#pragma unroll
  for (int j = 0; j < 4; ++j) {
    const int idx = j * 2048 + threadIdx.x * 8;
    const int c = g * 16 + (idx >> 9);
    const float sc = gw[c] * rstd;
    const float sh = gb[c] - mean * sc;
    u16 o[8];
#pragma unroll
    for (int e = 0; e < 8; ++e) o[e] = f2bf(xs[idx + e] * sc + sh);
    *reinterpret_cast<uint4*>(xn + (size_t)bg * 8192 + idx) = *reinterpret_cast<const uint4*>(o);
  }
}

// ---------- weight casts ----------
__global__ __launch_bounds__(256) void cast3_k(const float* __restrict__ a,
                                               const float* __restrict__ b2,
                                               const float* __restrict__ c,
                                               u16* __restrict__ oa, u16* __restrict__ ob,
                                               u16* __restrict__ oc) {
  const int which = blockIdx.x >> 7;
  const float* in = which == 0 ? a : (which == 1 ? b2 : c);
  u16* out = which == 0 ? oa : (which == 1 ? ob : oc);
  size_t base = (((size_t)(blockIdx.x & 127)) * 256 + threadIdx.x) * 8;
  float4 v0 = *reinterpret_cast<const float4*>(in + base);
  float4 v1 = *reinterpret_cast<const float4*>(in + base + 4);
  u16 o[8];
  o[0] = f2bf(v0.x); o[1] = f2bf(v0.y); o[2] = f2bf(v0.z); o[3] = f2bf(v0.w);
  o[4] = f2bf(v1.x); o[5] = f2bf(v1.y); o[6] = f2bf(v1.z); o[7] = f2bf(v1.w);
  *reinterpret_cast<uint4*>(out + base) = *reinterpret_cast<const uint4*>(o);
}

// ---------- 8-phase 256^2 GEMM: out[b,m,n] = sum_k A[m,k]*B[n,k] (+bias) ----------
// 512 thr / 8 waves as 2M x 4N: wave w -> rows (w>>2)*128..+127, cols (w&3)*64..+63.
// BK=64; LDS 128KB = 2 buf x {A[2 x 128x64], B[2 x 128x64]}. Phase (ks,cp):
// 16 MFMA (8 rowfrags x 2 colfrags); A-frags loaded at cp==0, held across cp==1.
// Counted vmcnt ledger (verified): prologue 10 in flight; steady {2,6,6,2}x2;
// stage->consume >= 3 phases; tail iteration drains with vmcnt(0) at P5.
// Swizzle: 16B-slot' = slot ^ (row&7) on 128B rows (both-sides, balanced banks).
// OUT_MODE: 0 bf16+bias[n]; 1 bf16+bias[m]; 2 f32 no bias.
template <int OUT_MODE>
__global__ __launch_bounds__(512, 1) void gemm256_k(const u16* __restrict__ A, size_t sA,
                                                    const u16* __restrict__ Bm, size_t sB,
                                                    const float* __restrict__ bias,
                                                    void* __restrict__ out, size_t sO) {
  __shared__ u16 smem[65536];     // u16 units. buf q at q*32768: A 0/8192, B 16384/24576
  const int d = blockIdx.x;       // 0..255
  const int wgid = (d & 7) * 32 + (d >> 3);      // XCD-bijective (256 % 8 == 0)
  const int b = wgid >> 2;
  const int tile = wgid & 3;
  const int tm = (tile >> 1) * 256, tn = (tile & 1) * 256;
  const u16* Ab = A + (size_t)b * sA;
  const u16* Bb = Bm + (size_t)b * sB;
  const int tid = threadIdx.x, w = tid >> 6, lane = tid & 63;
  const int rh = w >> 2, cw = w & 3;
  const int frow = lane & 15, cc = lane >> 4;
  f32x4 acc[8][4] = {};           // [rowfrag][colfrag]
  short8 af[8], bfr[2];

  // Stage one 128x64 half-tile (16KB): 2 gloads/thread; linear LDS dest,
  // inverse-swizzled global source (slot_ = dest_slot ^ (row&7)).
#define STAGEH(Lofs, Gp)                                                       \
  {                                                                            \
    const u16* gsrc_ = (Gp);                                                   \
    _Pragma("unroll")                                                          \
    for (int p_ = 0; p_ < 2; ++p_) {                                           \
      const int row_ = p_ * 64 + (tid >> 3);                                   \
      const int slot_ = (tid & 7) ^ (row_ & 7);                                \
      gload_lds16(gsrc_ + (size_t)row_ * 512 + slot_ * 8,                      \
                  &smem[(Lofs) + p_ * 4096 + tid * 8]);                        \
    }                                                                          \
  }

#define PHASE(VMN, QB, KS, CP, ...)                                            \
  {                                                                            \
    asm volatile("s_waitcnt vmcnt(" #VMN ")" ::: "memory");                    \
    __builtin_amdgcn_s_barrier();                                              \
    asm volatile("" ::: "memory");                                             \
    _Pragma("unroll")                                                          \
    for (int j_ = 0; j_ < 2; ++j_) {                                           \
      const int lrb_ = (cw & 1) * 64 + (CP) * 32 + j_ * 16 + frow;             \
      bfr[j_] = *reinterpret_cast<const short8*>(                              \
          &smem[(QB) + 16384 + (cw >> 1) * 8192 + lrb_ * 64 +                  \
                (((KS) * 4 + cc) ^ (lrb_ & 7)) * 8]);                          \
    }                                                                          \
    if ((CP) == 0) {                                                           \
      _Pragma("unroll")                                                        \
      for (int ri_ = 0; ri_ < 8; ++ri_) {                                      \
        const int lra_ = ri_ * 16 + frow;                                      \
        af[ri_] = *reinterpret_cast<const short8*>(                            \
            &smem[(QB) + rh * 8192 + lra_ * 64 +                               \
                  (((KS) * 4 + cc) ^ (lra_ & 7)) * 8]);                        \
      }                                                                        \
    }                                                                          \
    __VA_ARGS__                                                                \
    __builtin_amdgcn_s_setprio(1);                                             \
    _Pragma("unroll")                                                          \
    for (int ri_ = 0; ri_ < 8; ++ri_) {                                        \
      acc[ri_][(CP) * 2]     = mfma16(af[ri_], bfr[0], acc[ri_][(CP) * 2]);    \
      acc[ri_][(CP) * 2 + 1] = mfma16(af[ri_], bfr[1], acc[ri_][(CP) * 2 + 1]);\
    }                                                                          \
    __builtin_amdgcn_s_setprio(0);                                             \
    __builtin_amdgcn_s_barrier();                                              \
    asm volatile("" ::: "memory");                                             \
  }

  // Prologue: tile0 (k=0) -> buf0 all 4 halves; tile1 (k=64) Ah0 -> buf1.
  STAGEH(0,     Ab + (size_t)tm * 512);
  STAGEH(8192,  Ab + (size_t)(tm + 128) * 512);
  STAGEH(16384, Bb + (size_t)tn * 512);
  STAGEH(24576, Bb + (size_t)(tn + 128) * 512);
  STAGEH(32768, Ab + (size_t)tm * 512 + 64);

  for (int i = 0; i < 3; ++i) {   // full iterations: tiles 2i (buf0), 2i+1 (buf1)
    const int k0c1 = i * 128 + 64;
    const int k0n2 = i * 128 + 128;
    const int k0n3 = i * 128 + 192;
    PHASE(2, 0, 0, 0,
          STAGEH(40960, Ab + (size_t)(tm + 128) * 512 + k0c1);
          STAGEH(49152, Bb + (size_t)tn * 512 + k0c1);)
    PHASE(6, 0, 0, 1,
          STAGEH(57344, Bb + (size_t)(tn + 128) * 512 + k0c1);)
    PHASE(6, 0, 1, 0, )
    PHASE(2, 0, 1, 1,
          STAGEH(0, Ab + (size_t)tm * 512 + k0n2);)
    PHASE(2, 32768, 0, 0,
          STAGEH(8192,  Ab + (size_t)(tm + 128) * 512 + k0n2);
          STAGEH(16384, Bb + (size_t)tn * 512 + k0n2);)
    PHASE(6, 32768, 0, 1,
          STAGEH(24576, Bb + (size_t)(tn + 128) * 512 + k0n2);)
    PHASE(6, 32768, 1, 0, )
    PHASE(2, 32768, 1, 1,
          STAGEH(32768, Ab + (size_t)tm * 512 + k0n3);)
  }
  // Tail (i=3): stages only the last K-tile's remaining halves; P5 drains to 0.
  PHASE(2, 0, 0, 0,
        STAGEH(40960, Ab + (size_t)(tm + 128) * 512 + 448);
        STAGEH(49152, Bb + (size_t)tn * 512 + 448);)
  PHASE(6, 0, 0, 1,
        STAGEH(57344, Bb + (size_t)(tn + 128) * 512 + 448);)
  PHASE(6, 0, 1, 0, )
  PHASE(2, 0, 1, 1, )
  PHASE(0, 32768, 0, 0, )
  PHASE(0, 32768, 0, 1, )
  PHASE(0, 32768, 1, 0, )
  PHASE(0, 32768, 1, 1, )
#undef PHASE
#undef STAGEH

  const int col0 = lane & 15, row0 = (lane >> 4) * 4;
#pragma unroll
  for (int ri = 0; ri < 8; ++ri) {
#pragma unroll
    for (int cj = 0; cj < 4; ++cj) {
      const int gc = tn + cw * 64 + cj * 16 + col0;
      const float bv = (OUT_MODE == 0) ? bias[gc] : 0.f;
#pragma unroll
      for (int r = 0; r < 4; ++r) {
        const int gr = tm + rh * 128 + ri * 16 + row0 + r;
        float v = acc[ri][cj][r];
        if (OUT_MODE == 0) v += bv;
        if (OUT_MODE == 1) v += bias[gr];
        if (OUT_MODE == 2)
          ((float*)out)[(size_t)b * sO + (size_t)gr * 512 + gc] = v;
        else
          ((u16*)out)[(size_t)b * sO + (size_t)gr * 512 + gc] = f2bf(v);
      }
    }
  }
}

// ---------- scores + softmax -> P (R12 proven config, unchanged) ----------
__global__ __launch_bounds__(256, 2) void scores_softmax_k(const u16* __restrict__ Q,
                                                           const u16* __restrict__ K,
                                                           u16* __restrict__ P) {
  __shared__ u16 Qs[2][2048];
  __shared__ u16 Ks[2][16384];
  __shared__ float rmax[4][64], rsum[4][64];
  const int d = blockIdx.x;       // 0..511
  const int t = d >> 3;
  const int b = (d & 7) * 8 + (t >> 3);
  const int m0 = (t & 7) * 64;
  const u16* Qb = Q + (size_t)b * 262144 + (size_t)m0 * 512;
  const u16* Kb = K + (size_t)b * 262144;
  u16* Pb = P + (size_t)b * 262144;
  const int tid = threadIdx.x, kq = tid >> 6, lane = tid & 63;
  const int srow = lane >> 2;
  const int ssw = ((lane & 3) ^ ((lane >> 3) & 3)) * 8;
  f32x4 acc[4][8] = {};

#define SC_STAGE(bb, k0)                                                       \
  {                                                                            \
    _Pragma("unroll")                                                          \
    for (int s2 = 0; s2 < 8; ++s2) {                                           \
      const int c = kq * 8 + s2;                                               \
      gload_lds16(Kb + (size_t)(c * 16 + srow) * 512 + (k0) + ssw,             \
                  &Ks[bb][c * 512]);                                           \
    }                                                                          \
    gload_lds16(Qb + (size_t)(kq * 16 + srow) * 512 + (k0) + ssw,              \
                &Qs[bb][kq * 512]);                                            \
  }

  SC_STAGE(0, 0);
  SC_STAGE(1, 32);
  for (int ts = 0; ts < 16; ++ts) {
    const int cur = ts & 1;
    WAIT_ENTER(9, ts == 15);
    const int frow = lane & 15, cc = lane >> 4;
    short8 aq[4];
#pragma unroll
    for (int i = 0; i < 4; ++i)
      aq[i] = *lds_frag(Qs[cur], i * 16 + frow, cc);
#pragma unroll
    for (int j = 0; j < 8; ++j) {
      short8 bk = *lds_frag(Ks[cur], kq * 128 + j * 16 + frow, cc);
#pragma unroll
      for (int i = 0; i < 4; ++i)
        acc[i][j] = mfma16(aq[i], bk, acc[i][j]);
    }
    WAIT_EXIT();
    if (ts < 14) SC_STAGE(cur, (ts + 2) * 32);
  }
#undef SC_STAGE

  float pm[4][4];
#pragma unroll
  for (int i = 0; i < 4; ++i)
#pragma unroll
    for (int r = 0; r < 4; ++r) pm[i][r] = -1e30f;
#pragma unroll
  for (int i = 0; i < 4; ++i)
#pragma unroll
    for (int j = 0; j < 8; ++j)
#pragma unroll
      for (int r = 0; r < 4; ++r) {
        float v = acc[i][j][r] * SM_SCALE;
        acc[i][j][r] = v;
        pm[i][r] = fmaxf(pm[i][r], v);
      }
#pragma unroll
  for (int off = 1; off < 16; off <<= 1)
#pragma unroll
    for (int i = 0; i < 4; ++i)
#pragma unroll
      for (int r = 0; r < 4; ++r) pm[i][r] = fmaxf(pm[i][r], __shfl_xor(pm[i][r], off));
  if ((lane & 15) == 0) {
#pragma unroll
    for (int i = 0; i < 4; ++i)
#pragma unroll
      for (int r = 0; r < 4; ++r)
        rmax[kq][i * 16 + (lane >> 4) * 4 + r] = pm[i][r];
  }
  __syncthreads();
#pragma unroll
  for (int i = 0; i < 4; ++i)
#pragma unroll
    for (int r = 0; r < 4; ++r) {
      const int row = i * 16 + (lane >> 4) * 4 + r;
      pm[i][r] = fmaxf(fmaxf(rmax[0][row], rmax[1][row]), fmaxf(rmax[2][row], rmax[3][row]));
    }
  float ps[4][4];
#pragma unroll
  for (int i = 0; i < 4; ++i)
#pragma unroll
    for (int r = 0; r < 4; ++r) ps[i][r] = 0.f;
#pragma unroll
  for (int i = 0; i < 4; ++i)
#pragma unroll
    for (int j = 0; j < 8; ++j)
#pragma unroll
      for (int r = 0; r < 4; ++r) {
        float e = __expf(acc[i][j][r] - pm[i][r]);
        acc[i][j][r] = e;
        ps[i][r] += e;
      }
#pragma unroll
  for (int off = 1; off < 16; off <<= 1)
#pragma unroll
    for (int i = 0; i < 4; ++i)
#pragma unroll
      for (int r = 0; r < 4; ++r) ps[i][r] += __shfl_xor(ps[i][r], off);
  if ((lane & 15) == 0) {
#pragma unroll
    for (int i = 0; i < 4; ++i)
#pragma unroll
      for (int r = 0; r < 4; ++r)
        rsum[kq][i * 16 + (lane >> 4) * 4 + r] = ps[i][r];
  }
  __syncthreads();
#pragma unroll
  for (int i = 0; i < 4; ++i)
#pragma unroll
    for (int r = 0; r < 4; ++r) {
      const int row = i * 16 + (lane >> 4) * 4 + r;
      ps[i][r] = 1.0f / (rsum[0][row] + rsum[1][row] + rsum[2][row] + rsum[3][row]);
    }
#pragma unroll
  for (int i = 0; i < 4; ++i)
#pragma unroll
    for (int j = 0; j < 8; ++j) {
      const int gcol = kq * 128 + j * 16 + (lane & 15);
#pragma unroll
      for (int r = 0; r < 4; ++r) {
        const int grow = m0 + i * 16 + (lane >> 4) * 4 + r;
        Pb[(size_t)grow * 512 + gcol] = f2bf(acc[i][j][r] * ps[i][r]);
      }
    }
}

extern "C" void kernel_launch(void* const* d_in, const int* in_sizes, int n_in,
                              void* d_out, int out_size, void* d_ws, size_t ws_size,
                              hipStream_t stream) {
  const float* x = (const float*)d_in[0];
  const float* qw = (const float*)d_in[1];
  const float* qb = (const float*)d_in[2];
  const float* kw = (const float*)d_in[3];
  const float* kb = (const float*)d_in[4];
  const float* vw = (const float*)d_in[5];
  const float* vb = (const float*)d_in[6];
  const float* gnw = (const float*)d_in[7];
  const float* gnb = (const float*)d_in[8];

  char* ws = (char*)d_ws;
  u16* qwb = (u16*)(ws);
  u16* kwb = (u16*)(ws + 524288);
  u16* vwb = (u16*)(ws + 2 * 524288);
  u16* xn = (u16*)(ws + 4 * 524288);
  u16* Qb = xn + 16777216;
  u16* Kb = Qb + 16777216;
  u16* VT = Kb + 16777216;
  u16* P = xn;                       // xn dead after QKV
  float* out = (float*)d_out;

  gn_fused_k<<<dim3(2048), dim3(256), 0, stream>>>(x, gnw, gnb, xn);
  cast3_k<<<dim3(384), dim3(256), 0, stream>>>(qw, kw, vw, qwb, kwb, vwb);
  // Q = xn qw^T + qb ; K = xn kw^T + kb (bf16, col bias)
  gemm256_k<0><<<dim3(256), dim3(512), 0, stream>>>(xn, (size_t)262144, qwb, (size_t)0, qb, (void*)Qb, (size_t)262144);
  gemm256_k<0><<<dim3(256), dim3(512), 0, stream>>>(xn, (size_t)262144, kwb, (size_t)0, kb, (void*)Kb, (size_t)262144);
  // VT[b,d,c] = sum_k vw[d,k] xn[c,k] + vb[d] (bf16, row bias)
  gemm256_k<1><<<dim3(256), dim3(512), 0, stream>>>(vwb, (size_t)0, xn, (size_t)262144, vb, (void*)VT, (size_t)262144);
  // P = softmax(Q K^T * scale)
  scores_softmax_k<<<dim3(512), dim3(256), 0, stream>>>(Qb, Kb, P);
  // out[b,m,n] = sum_k P[m,k] VT[n,k] (f32)
  gemm256_k<2><<<dim3(256), dim3(512), 0, stream>>>(P, (size_t)262144, VT, (size_t)262144, (const float*)nullptr, (void*)out, (size_t)262144);
}